// Round 2
// baseline (2784.305 us; speedup 1.0000x reference)
//
#include <hip/hip_runtime.h>
#include <math.h>

#define TT  1024
#define DD  2048
#define NHH 2048
#define CC  1000

// ---------------------------------------------------------------------------
// GEMM: XH = x @ Wh^T ; XZ = x @ Wz^T + bz   (fp32, 64x64 tile, BK=32)
// grid (NHH/64, TT/64, 2); z=0 -> Wh/XH, z=1 -> Wz/XZ+bias
// ---------------------------------------------------------------------------
__global__ __launch_bounds__(256) void k_gemm(const float* __restrict__ X,
                                              const float* __restrict__ Wh,
                                              const float* __restrict__ Wz,
                                              const float* __restrict__ bz,
                                              float* __restrict__ XH,
                                              float* __restrict__ XZ) {
    __shared__ float As[32][68];   // [k][m]
    __shared__ float Bs[32][68];   // [k][n]
    const int z = blockIdx.z;
    const float* __restrict__ W = z ? Wz : Wh;
    float* __restrict__ OUT = z ? XZ : XH;
    const int n0 = blockIdx.x * 64;
    const int m0 = blockIdx.y * 64;
    const int tid = threadIdx.x;
    const int tx = tid & 15, ty = tid >> 4;
    const int lr = tid >> 2;           // 0..63 row within tile
    const int lc = (tid & 3) * 8;      // 0,8,16,24 col base

    float acc[4][4] = {};
    for (int k0 = 0; k0 < DD; k0 += 32) {
        float4 a0 = *(const float4*)&X[(size_t)(m0 + lr) * DD + k0 + lc];
        float4 a1 = *(const float4*)&X[(size_t)(m0 + lr) * DD + k0 + lc + 4];
        float4 b0 = *(const float4*)&W[(size_t)(n0 + lr) * DD + k0 + lc];
        float4 b1 = *(const float4*)&W[(size_t)(n0 + lr) * DD + k0 + lc + 4];
        As[lc+0][lr]=a0.x; As[lc+1][lr]=a0.y; As[lc+2][lr]=a0.z; As[lc+3][lr]=a0.w;
        As[lc+4][lr]=a1.x; As[lc+5][lr]=a1.y; As[lc+6][lr]=a1.z; As[lc+7][lr]=a1.w;
        Bs[lc+0][lr]=b0.x; Bs[lc+1][lr]=b0.y; Bs[lc+2][lr]=b0.z; Bs[lc+3][lr]=b0.w;
        Bs[lc+4][lr]=b1.x; Bs[lc+5][lr]=b1.y; Bs[lc+6][lr]=b1.z; Bs[lc+7][lr]=b1.w;
        __syncthreads();
#pragma unroll
        for (int kk = 0; kk < 32; ++kk) {
            float4 av = *(const float4*)&As[kk][ty * 4];
            float4 bv = *(const float4*)&Bs[kk][tx * 4];
            acc[0][0] = fmaf(av.x, bv.x, acc[0][0]); acc[0][1] = fmaf(av.x, bv.y, acc[0][1]);
            acc[0][2] = fmaf(av.x, bv.z, acc[0][2]); acc[0][3] = fmaf(av.x, bv.w, acc[0][3]);
            acc[1][0] = fmaf(av.y, bv.x, acc[1][0]); acc[1][1] = fmaf(av.y, bv.y, acc[1][1]);
            acc[1][2] = fmaf(av.y, bv.z, acc[1][2]); acc[1][3] = fmaf(av.y, bv.w, acc[1][3]);
            acc[2][0] = fmaf(av.z, bv.x, acc[2][0]); acc[2][1] = fmaf(av.z, bv.y, acc[2][1]);
            acc[2][2] = fmaf(av.z, bv.z, acc[2][2]); acc[2][3] = fmaf(av.z, bv.w, acc[2][3]);
            acc[3][0] = fmaf(av.w, bv.x, acc[3][0]); acc[3][1] = fmaf(av.w, bv.y, acc[3][1]);
            acc[3][2] = fmaf(av.w, bv.z, acc[3][2]); acc[3][3] = fmaf(av.w, bv.w, acc[3][3]);
        }
        __syncthreads();
    }
    float4 bias = make_float4(0.f, 0.f, 0.f, 0.f);
    if (z) bias = *(const float4*)&bz[n0 + tx * 4];
#pragma unroll
    for (int i = 0; i < 4; ++i) {
        float4 o = make_float4(acc[i][0] + bias.x, acc[i][1] + bias.y,
                               acc[i][2] + bias.z, acc[i][3] + bias.w);
        *(float4*)&OUT[(size_t)(m0 + ty * 4 + i) * NHH + n0 + tx * 4] = o;
    }
}

// ---------------------------------------------------------------------------
// Recurrent scan, 1 timestep per round (the proven schedule: validate of P_t
// happens one full round after its publish, so LLC visibility latency
// overlaps the matvec+gate compute of the next step).
// Round-2 lesson: 2-step pair rounds have ZERO publish->validate slack and
// regressed 35%; the 1-step pipeline already saturates the GRU's
// dependency-distance-2 slack.
//
// This version shortens the critical publish chain and halves gather traffic:
//  * per-wave gate fusion: wave w owns Uz rows {e0,e0+1} AND Uh rows
//    {e0,e0+1} (e0 = base16+2w). After the 64-lane butterfly reduce, lanes
//    0/1 hold (dz,dh) for their element locally -> gates + publish fire
//    straight away. No dot_s LDS round trip, no barrier before publish.
//  * double-buffered Hs: gather results write buf p^1 while matvec read
//    buf p -> exactly ONE __syncthreads per round.
//  * 128 WGs x 512 thr (1 WG/CU): same U-register budget (128 f32/lane),
//    16 owned elems/WG, 4 gather loads/thread (was 8). Total LLC gather
//    traffic halves (2 MB/round); publisher straggler-max over 128 not 256.
// Protocol unchanged: 4-slot tagged (epoch<<32|f32bits) exchange, relaxed
// agent-scope 64-bit atomics, overwrite distance 4 > pipeline depth 2.
// Tag monotone 1..1024 -> no cross-run ABA (slots rewritten by epoch 4).
// ---------------------------------------------------------------------------
__global__ __launch_bounds__(512, 1) void k_recur(
    const float* __restrict__ XH, const float* __restrict__ XZ,
    const float* __restrict__ Uh, const float* __restrict__ Uz,
    const float* __restrict__ zt0, const float* __restrict__ ht0,
    const float* __restrict__ hp0,
    unsigned long long* __restrict__ Hbuf) {
    __shared__ float Hs[2][NHH];
    const int tid  = threadIdx.x;
    const int wave = tid >> 6, lane = tid & 63;
    const int base16 = blockIdx.x * 16;
    const int e0 = base16 + 2 * wave;      // this wave's 2 elements: e0, e0+1

    // U rows in registers: u[0..1] = Uz rows e0,e0+1 ; u[2..3] = Uh rows
    float u[4][32];
#pragma unroll
    for (int r = 0; r < 2; ++r) {
        const float* __restrict__ rowz = Uz + (size_t)(e0 + r) * NHH;
        const float* __restrict__ rowh = Uh + (size_t)(e0 + r) * NHH;
#pragma unroll
        for (int c = 0; c < 8; ++c) {
            float4 vz = *(const float4*)&rowz[c * 256 + lane * 4];
            float4 vh = *(const float4*)&rowh[c * 256 + lane * 4];
            u[r][c*4+0]=vz.x; u[r][c*4+1]=vz.y; u[r][c*4+2]=vz.z; u[r][c*4+3]=vz.w;
            u[2+r][c*4+0]=vh.x; u[2+r][c*4+1]=vh.y; u[2+r][c*4+2]=vh.z; u[2+r][c*4+3]=vh.w;
        }
    }

    // Hs[0] = P_0 = hprev0
#pragma unroll
    for (int k = 0; k < 4; ++k) Hs[0][k * 512 + tid] = hp0[k * 512 + tid];

    // own P_1 from initial gates; publish epoch 1 (slot 1)
    float p_cur = 0.f;
    if (lane < 2) {
        const int e = e0 + lane;
        float z0 = zt0[e], g0 = ht0[e], p0 = hp0[e];
        p_cur = (1.0f - z0) * p0 + z0 * g0;
        __hip_atomic_store(&Hbuf[(size_t)1 * NHH + e],
            (1ull << 32) | (unsigned long long)__float_as_uint(p_cur),
            __ATOMIC_RELAXED, __HIP_MEMORY_SCOPE_AGENT);
    }
    __syncthreads();

    int p = 0;
    for (int t = 1; t < TT; ++t) {
        // (i) issue gather loads for epoch t (validated in (iv))
        const unsigned long long* __restrict__ src = Hbuf + (size_t)(t & 3) * NHH;
        unsigned long long pv[4];
#pragma unroll
        for (int k = 0; k < 4; ++k)
            pv[k] = __hip_atomic_load(&src[k * 512 + tid], __ATOMIC_RELAXED, __HIP_MEMORY_SCOPE_AGENT);
        float xzv = 0.f, xhv = 0.f;
        if (lane < 2) {
            xzv = XZ[(size_t)(t - 1) * NHH + e0 + lane];
            xhv = XH[(size_t)(t - 1) * NHH + e0 + lane];
        }

        // (ii) matvec on Hs[p] = P_{t-1}: 4 rows (2 Uz + 2 Uh), U in registers
        float a0 = 0.f, a1 = 0.f, a2 = 0.f, a3 = 0.f;
#pragma unroll
        for (int c = 0; c < 8; ++c) {
            float4 h4 = *(const float4*)&Hs[p][c * 256 + lane * 4];
            a0 = fmaf(u[0][c*4+0], h4.x, fmaf(u[0][c*4+1], h4.y, fmaf(u[0][c*4+2], h4.z, fmaf(u[0][c*4+3], h4.w, a0))));
            a1 = fmaf(u[1][c*4+0], h4.x, fmaf(u[1][c*4+1], h4.y, fmaf(u[1][c*4+2], h4.z, fmaf(u[1][c*4+3], h4.w, a1))));
            a2 = fmaf(u[2][c*4+0], h4.x, fmaf(u[2][c*4+1], h4.y, fmaf(u[2][c*4+2], h4.z, fmaf(u[2][c*4+3], h4.w, a2))));
            a3 = fmaf(u[3][c*4+0], h4.x, fmaf(u[3][c*4+1], h4.y, fmaf(u[3][c*4+2], h4.z, fmaf(u[3][c*4+3], h4.w, a3))));
        }
#pragma unroll
        for (int off = 32; off > 0; off >>= 1) {
            a0 += __shfl_xor(a0, off); a1 += __shfl_xor(a1, off);
            a2 += __shfl_xor(a2, off); a3 += __shfl_xor(a3, off);
        }
        // (iii) gates + publish, per-wave (butterfly leaves sums in ALL lanes)
        if (lane < 2) {
            float dz = lane ? a1 : a0;
            float dh = lane ? a3 : a2;
            float z = 1.0f / (1.0f + expf(-(xzv + dz)));
            float g = tanhf(xhv + dh);
            float pn = (1.0f - z) * p_cur + z * g;
            p_cur = pn;
            __hip_atomic_store(&Hbuf[(size_t)((t + 1) & 3) * NHH + e0 + lane],
                ((unsigned long long)(unsigned)(t + 1) << 32)
                    | (unsigned long long)__float_as_uint(pn),
                __ATOMIC_RELAXED, __HIP_MEMORY_SCOPE_AGENT);
        }
        if (t == TT - 1) break;   // epoch 1024 published; gather/Hs write dead

        // (iv) validate epoch-t tags; batched parallel retry of stale ones
        for (;;) {
            unsigned stale = 0;
#pragma unroll
            for (int k = 0; k < 4; ++k)
                if ((unsigned)(pv[k] >> 32) != (unsigned)t) stale |= (1u << k);
            if (!stale) break;
#pragma unroll
            for (int k = 0; k < 4; ++k)
                if (stale & (1u << k))
                    pv[k] = __hip_atomic_load(&src[k * 512 + tid], __ATOMIC_RELAXED, __HIP_MEMORY_SCOPE_AGENT);
        }
#pragma unroll
        for (int k = 0; k < 4; ++k)
            Hs[p ^ 1][k * 512 + tid] = __uint_as_float((unsigned)pv[k]);
        __syncthreads();
        p ^= 1;
    }
}

// ---------------------------------------------------------------------------
// logits[r] = Wout[r,:] . P_1024   (epoch 1024 -> slot 0, value in low bits)
// ---------------------------------------------------------------------------
__global__ __launch_bounds__(256) void k_logits(const unsigned long long* __restrict__ Hbuf,
                                                const float* __restrict__ Wout,
                                                float* __restrict__ lg) {
    __shared__ float Hs[NHH];
    const int tid = threadIdx.x;
    for (int k = tid; k < NHH; k += 256) Hs[k] = __uint_as_float((unsigned)Hbuf[k]);
    __syncthreads();
    const int wave = tid >> 6, lane = tid & 63;
    const int row = blockIdx.x * 4 + wave;
    float a = 0.f;
#pragma unroll
    for (int c = 0; c < 8; ++c) {
        float4 w = *(const float4*)&Wout[(size_t)row * NHH + c * 256 + lane * 4];
        float4 h = *(const float4*)&Hs[c * 256 + lane * 4];
        a = fmaf(w.x, h.x, fmaf(w.y, h.y, fmaf(w.z, h.z, fmaf(w.w, h.w, a))));
    }
#pragma unroll
    for (int off = 32; off > 0; off >>= 1) a += __shfl_xor(a, off);
    if (lane == 0) lg[row] = a;
}

// ---------------------------------------------------------------------------
// softmax over 1000 logits, single block
// ---------------------------------------------------------------------------
__global__ __launch_bounds__(1024) void k_softmax(const float* __restrict__ lg,
                                                  float* __restrict__ out) {
    const int i = threadIdx.x;
    __shared__ float red[16];
    __shared__ float bc[2];
    float v = (i < CC) ? lg[i] : -3.0e38f;
    float m = v;
#pragma unroll
    for (int off = 32; off > 0; off >>= 1) m = fmaxf(m, __shfl_xor(m, off));
    if ((i & 63) == 0) red[i >> 6] = m;
    __syncthreads();
    if (i == 0) { float mm = red[0]; for (int k = 1; k < 16; ++k) mm = fmaxf(mm, red[k]); bc[0] = mm; }
    __syncthreads();
    float e = (i < CC) ? expf(v - bc[0]) : 0.f;
    float s = e;
#pragma unroll
    for (int off = 32; off > 0; off >>= 1) s += __shfl_xor(s, off);
    if ((i & 63) == 0) red[i >> 6] = s;
    __syncthreads();
    if (i == 0) { float ss = 0.f; for (int k = 0; k < 16; ++k) ss += red[k]; bc[1] = ss; }
    __syncthreads();
    if (i < CC) out[i] = e / bc[1];
}

extern "C" void kernel_launch(void* const* d_in, const int* in_sizes, int n_in,
                              void* d_out, int out_size, void* d_ws, size_t ws_size,
                              hipStream_t stream) {
    const float* x    = (const float*)d_in[0];
    const float* Wh   = (const float*)d_in[1];
    const float* Wz   = (const float*)d_in[2];
    // d_in[3] = Wr  (dead code in reference)
    const float* Uh   = (const float*)d_in[4];
    const float* Uz   = (const float*)d_in[5];
    const float* bz   = (const float*)d_in[6];
    // d_in[7] = Ur, d_in[8] = br (dead code)
    const float* Wout = (const float*)d_in[9];
    // d_in[10] = h0 (overwritten before first use since T>=1)
    const float* zt0  = (const float*)d_in[11];
    const float* ht0  = (const float*)d_in[12];
    const float* hp0  = (const float*)d_in[13];
    float* out = (float*)d_out;

    float* XH = (float*)d_ws;                                   // T*NH f32
    float* XZ = XH + (size_t)TT * NHH;                          // T*NH f32
    unsigned long long* Hbuf = (unsigned long long*)(XZ + (size_t)TT * NHH); // 4*NH u64
    float* lg = (float*)(Hbuf + 4 * NHH);                       // CC f32

    k_gemm<<<dim3(NHH / 64, TT / 64, 2), dim3(256), 0, stream>>>(x, Wh, Wz, bz, XH, XZ);
    k_recur<<<dim3(128), dim3(512), 0, stream>>>(XH, XZ, Uh, Uz, zt0, ht0, hp0, Hbuf);
    k_logits<<<dim3(250), dim3(256), 0, stream>>>(Hbuf, Wout, lg);
    k_softmax<<<dim3(1), dim3(1024), 0, stream>>>(lg, out);
}

// Round 3
// 2423.630 us; speedup vs baseline: 1.1488x; 1.1488x over previous
//
#include <hip/hip_runtime.h>
#include <math.h>

#define TT  1024
#define DD  2048
#define NHH 2048
#define CC  1000

// ---------------------------------------------------------------------------
// GEMM: XH = x @ Wh^T ; XZ = x @ Wz^T + bz   (fp32, 64x64 tile, BK=32)
// grid (NHH/64, TT/64, 2); z=0 -> Wh/XH, z=1 -> Wz/XZ+bias
// ---------------------------------------------------------------------------
__global__ __launch_bounds__(256) void k_gemm(const float* __restrict__ X,
                                              const float* __restrict__ Wh,
                                              const float* __restrict__ Wz,
                                              const float* __restrict__ bz,
                                              float* __restrict__ XH,
                                              float* __restrict__ XZ) {
    __shared__ float As[32][68];   // [k][m]
    __shared__ float Bs[32][68];   // [k][n]
    const int z = blockIdx.z;
    const float* __restrict__ W = z ? Wz : Wh;
    float* __restrict__ OUT = z ? XZ : XH;
    const int n0 = blockIdx.x * 64;
    const int m0 = blockIdx.y * 64;
    const int tid = threadIdx.x;
    const int tx = tid & 15, ty = tid >> 4;
    const int lr = tid >> 2;           // 0..63 row within tile
    const int lc = (tid & 3) * 8;      // 0,8,16,24 col base

    float acc[4][4] = {};
    for (int k0 = 0; k0 < DD; k0 += 32) {
        float4 a0 = *(const float4*)&X[(size_t)(m0 + lr) * DD + k0 + lc];
        float4 a1 = *(const float4*)&X[(size_t)(m0 + lr) * DD + k0 + lc + 4];
        float4 b0 = *(const float4*)&W[(size_t)(n0 + lr) * DD + k0 + lc];
        float4 b1 = *(const float4*)&W[(size_t)(n0 + lr) * DD + k0 + lc + 4];
        As[lc+0][lr]=a0.x; As[lc+1][lr]=a0.y; As[lc+2][lr]=a0.z; As[lc+3][lr]=a0.w;
        As[lc+4][lr]=a1.x; As[lc+5][lr]=a1.y; As[lc+6][lr]=a1.z; As[lc+7][lr]=a1.w;
        Bs[lc+0][lr]=b0.x; Bs[lc+1][lr]=b0.y; Bs[lc+2][lr]=b0.z; Bs[lc+3][lr]=b0.w;
        Bs[lc+4][lr]=b1.x; Bs[lc+5][lr]=b1.y; Bs[lc+6][lr]=b1.z; Bs[lc+7][lr]=b1.w;
        __syncthreads();
#pragma unroll
        for (int kk = 0; kk < 32; ++kk) {
            float4 av = *(const float4*)&As[kk][ty * 4];
            float4 bv = *(const float4*)&Bs[kk][tx * 4];
            acc[0][0] = fmaf(av.x, bv.x, acc[0][0]); acc[0][1] = fmaf(av.x, bv.y, acc[0][1]);
            acc[0][2] = fmaf(av.x, bv.z, acc[0][2]); acc[0][3] = fmaf(av.x, bv.w, acc[0][3]);
            acc[1][0] = fmaf(av.y, bv.x, acc[1][0]); acc[1][1] = fmaf(av.y, bv.y, acc[1][1]);
            acc[1][2] = fmaf(av.y, bv.z, acc[1][2]); acc[1][3] = fmaf(av.y, bv.w, acc[1][3]);
            acc[2][0] = fmaf(av.z, bv.x, acc[2][0]); acc[2][1] = fmaf(av.z, bv.y, acc[2][1]);
            acc[2][2] = fmaf(av.z, bv.z, acc[2][2]); acc[2][3] = fmaf(av.z, bv.w, acc[2][3]);
            acc[3][0] = fmaf(av.w, bv.x, acc[3][0]); acc[3][1] = fmaf(av.w, bv.y, acc[3][1]);
            acc[3][2] = fmaf(av.w, bv.z, acc[3][2]); acc[3][3] = fmaf(av.w, bv.w, acc[3][3]);
        }
        __syncthreads();
    }
    float4 bias = make_float4(0.f, 0.f, 0.f, 0.f);
    if (z) bias = *(const float4*)&bz[n0 + tx * 4];
#pragma unroll
    for (int i = 0; i < 4; ++i) {
        float4 o = make_float4(acc[i][0] + bias.x, acc[i][1] + bias.y,
                               acc[i][2] + bias.z, acc[i][3] + bias.w);
        *(float4*)&OUT[(size_t)(m0 + ty * 4 + i) * NHH + n0 + tx * 4] = o;
    }
}

// ---------------------------------------------------------------------------
// Recurrent scan, 1 timestep per round. Proven structure: 256 WGs x 256 thr
// (1 WG/CU, 1 wave/SIMD — round-2 lesson: halving CUs doubles per-CU
// critical-path compute and regresses 40%; per-CU work is sacred).
//
// Deltas vs the 1745us baseline:
//  * SYSTEM-scope publish stores (sc0+sc1): write the published line THROUGH
//    the XCD-local L2 to the shared coherence point, so remote agent-scope
//    polls L2-miss -> LLC-hit instead of paying a cross-XCD dirty-L2 probe.
//    Theory: that probe (~1.2us) is the dominant term of the 1.70us round.
//  * per-wave gate fusion: wave w owns elements {base8+2w, +1} with BOTH
//    Uz and Uh rows (u[0..1]=Uz, u[2..3]=Uh, 128 f32/lane). After the
//    64-lane butterfly, lanes 0/1 hold (dz,dh) locally -> gates + publish
//    immediately, no dot_s LDS round trip, no pre-publish barrier.
//  * double-buffered Hs -> exactly ONE __syncthreads per round.
//  * last round skips the dead validate/Hs-write.
// Protocol: 4-slot tagged (epoch<<32|f32bits) exchange, relaxed atomics,
// publish->validate slack = 1 full round (round-1 lesson: never validate a
// tag published in the same round). Overwrite distance 4 > pipeline depth 2;
// slot s is rewritten with epoch t+4 only after its writer validated epoch
// t+2, which implies every WG finished reading epoch t. Same-address
// coherence ordering kills cross-run ABA.
// ---------------------------------------------------------------------------
__global__ __launch_bounds__(256, 1) void k_recur(
    const float* __restrict__ XH, const float* __restrict__ XZ,
    const float* __restrict__ Uh, const float* __restrict__ Uz,
    const float* __restrict__ zt0, const float* __restrict__ ht0,
    const float* __restrict__ hp0,
    unsigned long long* __restrict__ Hbuf) {
    __shared__ float Hs[2][NHH];
    const int tid  = threadIdx.x;
    const int wave = tid >> 6, lane = tid & 63;
    const int base8 = blockIdx.x * 8;
    const int e0 = base8 + 2 * wave;       // this wave's 2 elements: e0, e0+1

    // U rows in registers: u[0..1] = Uz rows e0,e0+1 ; u[2..3] = Uh rows
    float u[4][32];
#pragma unroll
    for (int r = 0; r < 2; ++r) {
        const float* __restrict__ rowz = Uz + (size_t)(e0 + r) * NHH;
        const float* __restrict__ rowh = Uh + (size_t)(e0 + r) * NHH;
#pragma unroll
        for (int c = 0; c < 8; ++c) {
            float4 vz = *(const float4*)&rowz[c * 256 + lane * 4];
            float4 vh = *(const float4*)&rowh[c * 256 + lane * 4];
            u[r][c*4+0]=vz.x; u[r][c*4+1]=vz.y; u[r][c*4+2]=vz.z; u[r][c*4+3]=vz.w;
            u[2+r][c*4+0]=vh.x; u[2+r][c*4+1]=vh.y; u[2+r][c*4+2]=vh.z; u[2+r][c*4+3]=vh.w;
        }
    }

    // Hs[0] = P_0 = hprev0
#pragma unroll
    for (int k = 0; k < 8; ++k) Hs[0][k * 256 + tid] = hp0[k * 256 + tid];

    // own P_1 from initial gates; publish epoch 1 (slot 1), system scope
    float p_cur = 0.f;
    if (lane < 2) {
        const int e = e0 + lane;
        float z0 = zt0[e], g0 = ht0[e], p0 = hp0[e];
        p_cur = (1.0f - z0) * p0 + z0 * g0;
        __hip_atomic_store(&Hbuf[(size_t)1 * NHH + e],
            (1ull << 32) | (unsigned long long)__float_as_uint(p_cur),
            __ATOMIC_RELAXED, __HIP_MEMORY_SCOPE_SYSTEM);
    }
    __syncthreads();

    int p = 0;
    for (int t = 1; t < TT; ++t) {
        // (i) issue gather loads for epoch t (validated in (iv))
        const unsigned long long* __restrict__ src = Hbuf + (size_t)(t & 3) * NHH;
        unsigned long long pv[8];
#pragma unroll
        for (int k = 0; k < 8; ++k)
            pv[k] = __hip_atomic_load(&src[k * 256 + tid], __ATOMIC_RELAXED, __HIP_MEMORY_SCOPE_AGENT);
        float xzv = 0.f, xhv = 0.f;
        if (lane < 2) {
            xzv = XZ[(size_t)(t - 1) * NHH + e0 + lane];
            xhv = XH[(size_t)(t - 1) * NHH + e0 + lane];
        }

        // (ii) matvec on Hs[p] = P_{t-1}: 4 rows (2 Uz + 2 Uh), U in registers
        float a0 = 0.f, a1 = 0.f, a2 = 0.f, a3 = 0.f;
#pragma unroll
        for (int c = 0; c < 8; ++c) {
            float4 h4 = *(const float4*)&Hs[p][c * 256 + lane * 4];
            a0 = fmaf(u[0][c*4+0], h4.x, fmaf(u[0][c*4+1], h4.y, fmaf(u[0][c*4+2], h4.z, fmaf(u[0][c*4+3], h4.w, a0))));
            a1 = fmaf(u[1][c*4+0], h4.x, fmaf(u[1][c*4+1], h4.y, fmaf(u[1][c*4+2], h4.z, fmaf(u[1][c*4+3], h4.w, a1))));
            a2 = fmaf(u[2][c*4+0], h4.x, fmaf(u[2][c*4+1], h4.y, fmaf(u[2][c*4+2], h4.z, fmaf(u[2][c*4+3], h4.w, a2))));
            a3 = fmaf(u[3][c*4+0], h4.x, fmaf(u[3][c*4+1], h4.y, fmaf(u[3][c*4+2], h4.z, fmaf(u[3][c*4+3], h4.w, a3))));
        }
#pragma unroll
        for (int off = 32; off > 0; off >>= 1) {
            a0 += __shfl_xor(a0, off); a1 += __shfl_xor(a1, off);
            a2 += __shfl_xor(a2, off); a3 += __shfl_xor(a3, off);
        }
        // (iii) gates + publish per-wave (butterfly leaves sums in ALL lanes)
        if (lane < 2) {
            float dz = lane ? a1 : a0;
            float dh = lane ? a3 : a2;
            float z = 1.0f / (1.0f + expf(-(xzv + dz)));
            float g = tanhf(xhv + dh);
            float pn = (1.0f - z) * p_cur + z * g;
            p_cur = pn;
            __hip_atomic_store(&Hbuf[(size_t)((t + 1) & 3) * NHH + e0 + lane],
                ((unsigned long long)(unsigned)(t + 1) << 32)
                    | (unsigned long long)__float_as_uint(pn),
                __ATOMIC_RELAXED, __HIP_MEMORY_SCOPE_SYSTEM);
        }
        if (t == TT - 1) break;   // epoch 1024 published; rest of round is dead

        // (iv) validate epoch-t tags; batched parallel retry of stale ones
        for (;;) {
            unsigned stale = 0;
#pragma unroll
            for (int k = 0; k < 8; ++k)
                if ((unsigned)(pv[k] >> 32) != (unsigned)t) stale |= (1u << k);
            if (!stale) break;
#pragma unroll
            for (int k = 0; k < 8; ++k)
                if (stale & (1u << k))
                    pv[k] = __hip_atomic_load(&src[k * 256 + tid], __ATOMIC_RELAXED, __HIP_MEMORY_SCOPE_AGENT);
        }
#pragma unroll
        for (int k = 0; k < 8; ++k)
            Hs[p ^ 1][k * 256 + tid] = __uint_as_float((unsigned)pv[k]);
        __syncthreads();
        p ^= 1;
    }
}

// ---------------------------------------------------------------------------
// logits[r] = Wout[r,:] . P_1024   (epoch 1024 -> slot 0, value in low bits)
// ---------------------------------------------------------------------------
__global__ __launch_bounds__(256) void k_logits(const unsigned long long* __restrict__ Hbuf,
                                                const float* __restrict__ Wout,
                                                float* __restrict__ lg) {
    __shared__ float Hs[NHH];
    const int tid = threadIdx.x;
    for (int k = tid; k < NHH; k += 256) Hs[k] = __uint_as_float((unsigned)Hbuf[k]);
    __syncthreads();
    const int wave = tid >> 6, lane = tid & 63;
    const int row = blockIdx.x * 4 + wave;
    float a = 0.f;
#pragma unroll
    for (int c = 0; c < 8; ++c) {
        float4 w = *(const float4*)&Wout[(size_t)row * NHH + c * 256 + lane * 4];
        float4 h = *(const float4*)&Hs[c * 256 + lane * 4];
        a = fmaf(w.x, h.x, fmaf(w.y, h.y, fmaf(w.z, h.z, fmaf(w.w, h.w, a))));
    }
#pragma unroll
    for (int off = 32; off > 0; off >>= 1) a += __shfl_xor(a, off);
    if (lane == 0) lg[row] = a;
}

// ---------------------------------------------------------------------------
// softmax over 1000 logits, single block
// ---------------------------------------------------------------------------
__global__ __launch_bounds__(1024) void k_softmax(const float* __restrict__ lg,
                                                  float* __restrict__ out) {
    const int i = threadIdx.x;
    __shared__ float red[16];
    __shared__ float bc[2];
    float v = (i < CC) ? lg[i] : -3.0e38f;
    float m = v;
#pragma unroll
    for (int off = 32; off > 0; off >>= 1) m = fmaxf(m, __shfl_xor(m, off));
    if ((i & 63) == 0) red[i >> 6] = m;
    __syncthreads();
    if (i == 0) { float mm = red[0]; for (int k = 1; k < 16; ++k) mm = fmaxf(mm, red[k]); bc[0] = mm; }
    __syncthreads();
    float e = (i < CC) ? expf(v - bc[0]) : 0.f;
    float s = e;
#pragma unroll
    for (int off = 32; off > 0; off >>= 1) s += __shfl_xor(s, off);
    if ((i & 63) == 0) red[i >> 6] = s;
    __syncthreads();
    if (i == 0) { float ss = 0.f; for (int k = 0; k < 16; ++k) ss += red[k]; bc[1] = ss; }
    __syncthreads();
    if (i < CC) out[i] = e / bc[1];
}

extern "C" void kernel_launch(void* const* d_in, const int* in_sizes, int n_in,
                              void* d_out, int out_size, void* d_ws, size_t ws_size,
                              hipStream_t stream) {
    const float* x    = (const float*)d_in[0];
    const float* Wh   = (const float*)d_in[1];
    const float* Wz   = (const float*)d_in[2];
    // d_in[3] = Wr  (dead code in reference)
    const float* Uh   = (const float*)d_in[4];
    const float* Uz   = (const float*)d_in[5];
    const float* bz   = (const float*)d_in[6];
    // d_in[7] = Ur, d_in[8] = br (dead code)
    const float* Wout = (const float*)d_in[9];
    // d_in[10] = h0 (overwritten before first use since T>=1)
    const float* zt0  = (const float*)d_in[11];
    const float* ht0  = (const float*)d_in[12];
    const float* hp0  = (const float*)d_in[13];
    float* out = (float*)d_out;

    float* XH = (float*)d_ws;                                   // T*NH f32
    float* XZ = XH + (size_t)TT * NHH;                          // T*NH f32
    unsigned long long* Hbuf = (unsigned long long*)(XZ + (size_t)TT * NHH); // 4*NH u64
    float* lg = (float*)(Hbuf + 4 * NHH);                       // CC f32

    k_gemm<<<dim3(NHH / 64, TT / 64, 2), dim3(256), 0, stream>>>(x, Wh, Wz, bz, XH, XZ);
    k_recur<<<dim3(256), dim3(256), 0, stream>>>(XH, XZ, Uh, Uz, zt0, ht0, hp0, Hbuf);
    k_logits<<<dim3(250), dim3(256), 0, stream>>>(Hbuf, Wout, lg);
    k_softmax<<<dim3(1), dim3(1024), 0, stream>>>(lg, out);
}

// Round 4
// 2318.364 us; speedup vs baseline: 1.2010x; 1.0454x over previous
//
#include <hip/hip_runtime.h>
#include <math.h>

#define TT  1024
#define DD  2048
#define NHH 2048
#define CC  1000

// Hbuf layout: 4 slots x 256 WGs x 16 u64 (128B line per WG per slot, 8 used)
// -> every published line has a SINGLE writer WG (4 waves, one CU, one XCD L2).
#define SLOT_U64 4096   // 256 * 16

// ---------------------------------------------------------------------------
// GEMM: XH = x @ Wh^T ; XZ = x @ Wz^T + bz   (fp32, 64x64 tile, BK=32)
// grid (NHH/64, TT/64, 2); z=0 -> Wh/XH, z=1 -> Wz/XZ+bias
// ---------------------------------------------------------------------------
__global__ __launch_bounds__(256) void k_gemm(const float* __restrict__ X,
                                              const float* __restrict__ Wh,
                                              const float* __restrict__ Wz,
                                              const float* __restrict__ bz,
                                              float* __restrict__ XH,
                                              float* __restrict__ XZ) {
    __shared__ float As[32][68];   // [k][m]
    __shared__ float Bs[32][68];   // [k][n]
    const int z = blockIdx.z;
    const float* __restrict__ W = z ? Wz : Wh;
    float* __restrict__ OUT = z ? XZ : XH;
    const int n0 = blockIdx.x * 64;
    const int m0 = blockIdx.y * 64;
    const int tid = threadIdx.x;
    const int tx = tid & 15, ty = tid >> 4;
    const int lr = tid >> 2;           // 0..63 row within tile
    const int lc = (tid & 3) * 8;      // 0,8,16,24 col base

    float acc[4][4] = {};
    for (int k0 = 0; k0 < DD; k0 += 32) {
        float4 a0 = *(const float4*)&X[(size_t)(m0 + lr) * DD + k0 + lc];
        float4 a1 = *(const float4*)&X[(size_t)(m0 + lr) * DD + k0 + lc + 4];
        float4 b0 = *(const float4*)&W[(size_t)(n0 + lr) * DD + k0 + lc];
        float4 b1 = *(const float4*)&W[(size_t)(n0 + lr) * DD + k0 + lc + 4];
        As[lc+0][lr]=a0.x; As[lc+1][lr]=a0.y; As[lc+2][lr]=a0.z; As[lc+3][lr]=a0.w;
        As[lc+4][lr]=a1.x; As[lc+5][lr]=a1.y; As[lc+6][lr]=a1.z; As[lc+7][lr]=a1.w;
        Bs[lc+0][lr]=b0.x; Bs[lc+1][lr]=b0.y; Bs[lc+2][lr]=b0.z; Bs[lc+3][lr]=b0.w;
        Bs[lc+4][lr]=b1.x; Bs[lc+5][lr]=b1.y; Bs[lc+6][lr]=b1.z; Bs[lc+7][lr]=b1.w;
        __syncthreads();
#pragma unroll
        for (int kk = 0; kk < 32; ++kk) {
            float4 av = *(const float4*)&As[kk][ty * 4];
            float4 bv = *(const float4*)&Bs[kk][tx * 4];
            acc[0][0] = fmaf(av.x, bv.x, acc[0][0]); acc[0][1] = fmaf(av.x, bv.y, acc[0][1]);
            acc[0][2] = fmaf(av.x, bv.z, acc[0][2]); acc[0][3] = fmaf(av.x, bv.w, acc[0][3]);
            acc[1][0] = fmaf(av.y, bv.x, acc[1][0]); acc[1][1] = fmaf(av.y, bv.y, acc[1][1]);
            acc[1][2] = fmaf(av.y, bv.z, acc[1][2]); acc[1][3] = fmaf(av.y, bv.w, acc[1][3]);
            acc[2][0] = fmaf(av.z, bv.x, acc[2][0]); acc[2][1] = fmaf(av.z, bv.y, acc[2][1]);
            acc[2][2] = fmaf(av.z, bv.z, acc[2][2]); acc[2][3] = fmaf(av.z, bv.w, acc[2][3]);
            acc[3][0] = fmaf(av.w, bv.x, acc[3][0]); acc[3][1] = fmaf(av.w, bv.y, acc[3][1]);
            acc[3][2] = fmaf(av.w, bv.z, acc[3][2]); acc[3][3] = fmaf(av.w, bv.w, acc[3][3]);
        }
        __syncthreads();
    }
    float4 bias = make_float4(0.f, 0.f, 0.f, 0.f);
    if (z) bias = *(const float4*)&bz[n0 + tx * 4];
#pragma unroll
    for (int i = 0; i < 4; ++i) {
        float4 o = make_float4(acc[i][0] + bias.x, acc[i][1] + bias.y,
                               acc[i][2] + bias.z, acc[i][3] + bias.w);
        *(float4*)&OUT[(size_t)(m0 + ty * 4 + i) * NHH + n0 + tx * 4] = o;
    }
}

// ---------------------------------------------------------------------------
// Recurrent scan, 1 timestep per round. 256 WGs x 256 thr (1 WG/CU, 1
// wave/SIMD — round-2 lesson: per-CU critical-path work is sacred).
// Steady-state model from rounds 0-3:  R = max(C_round, L_vis); measured
// L_vis(agent-relaxed) ~1.7us, L_vis(system) ~2.0us (write-through to HBM,
// WRITE_SIZE doubled — round-3 lesson: publish must stop at the coherence
// point, keep AGENT scope).
// This round attacks L_vis itself: the old Hbuf packed 16 elements/line =
// 2 WGs (different XCDs) x 4 waves all storing into ONE 128B line per round
// -> cross-die ownership ping-pong at the coherence point. New layout gives
// each WG a private 128B line per slot (single-writer line, 4 waves on one
// XCD L2): stores merge locally, one fabric trip per line per round.
//  * per-wave gate fusion (kept from r3): wave w owns elements
//    {8wg+2w, +1} with both Uz+Uh rows in VGPRs; after the 64-lane
//    butterfly, lanes 0/1 publish immediately. No dot_s, ONE barrier/round.
//  * XH/XZ prefetched one full round ahead (HBM latency off the gate path).
// Protocol: 4-slot tagged (epoch<<32|f32bits), relaxed agent atomics,
// publish->validate slack = 1 round (round-1 lesson: never validate what
// you published this round). Overwrite distance 4 > pipeline depth 2.
// ---------------------------------------------------------------------------
__global__ __launch_bounds__(256, 1) void k_recur(
    const float* __restrict__ XH, const float* __restrict__ XZ,
    const float* __restrict__ Uh, const float* __restrict__ Uz,
    const float* __restrict__ zt0, const float* __restrict__ ht0,
    const float* __restrict__ hp0,
    unsigned long long* __restrict__ Hbuf) {
    __shared__ float Hs[2][NHH];
    const int tid  = threadIdx.x;
    const int wave = tid >> 6, lane = tid & 63;
    const int wg   = blockIdx.x;
    const int base8 = wg * 8;
    const int e0 = base8 + 2 * wave;       // this wave's 2 elements: e0, e0+1

    // U rows in registers: u[0..1] = Uz rows e0,e0+1 ; u[2..3] = Uh rows
    float u[4][32];
#pragma unroll
    for (int r = 0; r < 2; ++r) {
        const float* __restrict__ rowz = Uz + (size_t)(e0 + r) * NHH;
        const float* __restrict__ rowh = Uh + (size_t)(e0 + r) * NHH;
#pragma unroll
        for (int c = 0; c < 8; ++c) {
            float4 vz = *(const float4*)&rowz[c * 256 + lane * 4];
            float4 vh = *(const float4*)&rowh[c * 256 + lane * 4];
            u[r][c*4+0]=vz.x; u[r][c*4+1]=vz.y; u[r][c*4+2]=vz.z; u[r][c*4+3]=vz.w;
            u[2+r][c*4+0]=vh.x; u[2+r][c*4+1]=vh.y; u[2+r][c*4+2]=vh.z; u[2+r][c*4+3]=vh.w;
        }
    }

    // Hs[0] = P_0 = hprev0
#pragma unroll
    for (int k = 0; k < 8; ++k) Hs[0][k * 256 + tid] = hp0[k * 256 + tid];

    // own P_1 from initial gates; publish epoch 1 (slot 1), own 128B line
    float p_cur = 0.f;
    if (lane < 2) {
        const int e = e0 + lane;
        float z0 = zt0[e], g0 = ht0[e], p0 = hp0[e];
        p_cur = (1.0f - z0) * p0 + z0 * g0;
        __hip_atomic_store(&Hbuf[(size_t)1 * SLOT_U64 + wg * 16 + 2 * wave + lane],
            (1ull << 32) | (unsigned long long)__float_as_uint(p_cur),
            __ATOMIC_RELAXED, __HIP_MEMORY_SCOPE_AGENT);
    }
    // prefetch XH/XZ for t=1
    float xz_n = 0.f, xh_n = 0.f;
    if (lane < 2) {
        xz_n = XZ[e0 + lane];
        xh_n = XH[e0 + lane];
    }
    __syncthreads();

    int p = 0;
    for (int t = 1; t < TT; ++t) {
        // (i) issue gather loads for epoch t (validated in (iv));
        //     element e lives at line (e>>3), word (e&7)
        const unsigned long long* __restrict__ src = Hbuf + (size_t)(t & 3) * SLOT_U64;
        unsigned long long pv[8];
#pragma unroll
        for (int k = 0; k < 8; ++k) {
            const int e = k * 256 + tid;
            pv[k] = __hip_atomic_load(&src[(e >> 3) * 16 + (e & 7)],
                                      __ATOMIC_RELAXED, __HIP_MEMORY_SCOPE_AGENT);
        }
        const float xzv = xz_n, xhv = xh_n;
        if (lane < 2 && t < TT - 1) {   // prefetch next round's x-projections
            xz_n = XZ[(size_t)t * NHH + e0 + lane];
            xh_n = XH[(size_t)t * NHH + e0 + lane];
        }

        // (ii) matvec on Hs[p] = P_{t-1}: 4 rows (2 Uz + 2 Uh), U in registers
        float a0 = 0.f, a1 = 0.f, a2 = 0.f, a3 = 0.f;
#pragma unroll
        for (int c = 0; c < 8; ++c) {
            float4 h4 = *(const float4*)&Hs[p][c * 256 + lane * 4];
            a0 = fmaf(u[0][c*4+0], h4.x, fmaf(u[0][c*4+1], h4.y, fmaf(u[0][c*4+2], h4.z, fmaf(u[0][c*4+3], h4.w, a0))));
            a1 = fmaf(u[1][c*4+0], h4.x, fmaf(u[1][c*4+1], h4.y, fmaf(u[1][c*4+2], h4.z, fmaf(u[1][c*4+3], h4.w, a1))));
            a2 = fmaf(u[2][c*4+0], h4.x, fmaf(u[2][c*4+1], h4.y, fmaf(u[2][c*4+2], h4.z, fmaf(u[2][c*4+3], h4.w, a2))));
            a3 = fmaf(u[3][c*4+0], h4.x, fmaf(u[3][c*4+1], h4.y, fmaf(u[3][c*4+2], h4.z, fmaf(u[3][c*4+3], h4.w, a3))));
        }
#pragma unroll
        for (int off = 32; off > 0; off >>= 1) {
            a0 += __shfl_xor(a0, off); a1 += __shfl_xor(a1, off);
            a2 += __shfl_xor(a2, off); a3 += __shfl_xor(a3, off);
        }
        // (iii) gates + publish per-wave (butterfly leaves sums in ALL lanes)
        if (lane < 2) {
            float dz = lane ? a1 : a0;
            float dh = lane ? a3 : a2;
            float z = 1.0f / (1.0f + expf(-(xzv + dz)));
            float g = tanhf(xhv + dh);
            float pn = (1.0f - z) * p_cur + z * g;
            p_cur = pn;
            __hip_atomic_store(
                &Hbuf[(size_t)((t + 1) & 3) * SLOT_U64 + wg * 16 + 2 * wave + lane],
                ((unsigned long long)(unsigned)(t + 1) << 32)
                    | (unsigned long long)__float_as_uint(pn),
                __ATOMIC_RELAXED, __HIP_MEMORY_SCOPE_AGENT);
        }
        if (t == TT - 1) break;   // epoch 1024 published; rest of round is dead

        // (iv) validate epoch-t tags; batched parallel retry of stale ones
        for (;;) {
            unsigned stale = 0;
#pragma unroll
            for (int k = 0; k < 8; ++k)
                if ((unsigned)(pv[k] >> 32) != (unsigned)t) stale |= (1u << k);
            if (!stale) break;
#pragma unroll
            for (int k = 0; k < 8; ++k)
                if (stale & (1u << k)) {
                    const int e = k * 256 + tid;
                    pv[k] = __hip_atomic_load(&src[(e >> 3) * 16 + (e & 7)],
                                              __ATOMIC_RELAXED, __HIP_MEMORY_SCOPE_AGENT);
                }
        }
#pragma unroll
        for (int k = 0; k < 8; ++k)
            Hs[p ^ 1][k * 256 + tid] = __uint_as_float((unsigned)pv[k]);
        __syncthreads();
        p ^= 1;
    }
}

// ---------------------------------------------------------------------------
// logits[r] = Wout[r,:] . P_1024   (epoch 1024 -> slot 0, padded layout)
// ---------------------------------------------------------------------------
__global__ __launch_bounds__(256) void k_logits(const unsigned long long* __restrict__ Hbuf,
                                                const float* __restrict__ Wout,
                                                float* __restrict__ lg) {
    __shared__ float Hs[NHH];
    const int tid = threadIdx.x;
    for (int k = tid; k < NHH; k += 256)
        Hs[k] = __uint_as_float((unsigned)Hbuf[(k >> 3) * 16 + (k & 7)]);
    __syncthreads();
    const int wave = tid >> 6, lane = tid & 63;
    const int row = blockIdx.x * 4 + wave;
    float a = 0.f;
#pragma unroll
    for (int c = 0; c < 8; ++c) {
        float4 w = *(const float4*)&Wout[(size_t)row * NHH + c * 256 + lane * 4];
        float4 h = *(const float4*)&Hs[c * 256 + lane * 4];
        a = fmaf(w.x, h.x, fmaf(w.y, h.y, fmaf(w.z, h.z, fmaf(w.w, h.w, a))));
    }
#pragma unroll
    for (int off = 32; off > 0; off >>= 1) a += __shfl_xor(a, off);
    if (lane == 0) lg[row] = a;
}

// ---------------------------------------------------------------------------
// softmax over 1000 logits, single block
// ---------------------------------------------------------------------------
__global__ __launch_bounds__(1024) void k_softmax(const float* __restrict__ lg,
                                                  float* __restrict__ out) {
    const int i = threadIdx.x;
    __shared__ float red[16];
    __shared__ float bc[2];
    float v = (i < CC) ? lg[i] : -3.0e38f;
    float m = v;
#pragma unroll
    for (int off = 32; off > 0; off >>= 1) m = fmaxf(m, __shfl_xor(m, off));
    if ((i & 63) == 0) red[i >> 6] = m;
    __syncthreads();
    if (i == 0) { float mm = red[0]; for (int k = 1; k < 16; ++k) mm = fmaxf(mm, red[k]); bc[0] = mm; }
    __syncthreads();
    float e = (i < CC) ? expf(v - bc[0]) : 0.f;
    float s = e;
#pragma unroll
    for (int off = 32; off > 0; off >>= 1) s += __shfl_xor(s, off);
    if ((i & 63) == 0) red[i >> 6] = s;
    __syncthreads();
    if (i == 0) { float ss = 0.f; for (int k = 0; k < 16; ++k) ss += red[k]; bc[1] = ss; }
    __syncthreads();
    if (i < CC) out[i] = e / bc[1];
}

extern "C" void kernel_launch(void* const* d_in, const int* in_sizes, int n_in,
                              void* d_out, int out_size, void* d_ws, size_t ws_size,
                              hipStream_t stream) {
    const float* x    = (const float*)d_in[0];
    const float* Wh   = (const float*)d_in[1];
    const float* Wz   = (const float*)d_in[2];
    // d_in[3] = Wr  (dead code in reference)
    const float* Uh   = (const float*)d_in[4];
    const float* Uz   = (const float*)d_in[5];
    const float* bz   = (const float*)d_in[6];
    // d_in[7] = Ur, d_in[8] = br (dead code)
    const float* Wout = (const float*)d_in[9];
    // d_in[10] = h0 (overwritten before first use since T>=1)
    const float* zt0  = (const float*)d_in[11];
    const float* ht0  = (const float*)d_in[12];
    const float* hp0  = (const float*)d_in[13];
    float* out = (float*)d_out;

    float* XH = (float*)d_ws;                                   // T*NH f32
    float* XZ = XH + (size_t)TT * NHH;                          // T*NH f32
    unsigned long long* Hbuf = (unsigned long long*)(XZ + (size_t)TT * NHH); // 4*SLOT_U64 u64
    float* lg = (float*)(Hbuf + 4 * SLOT_U64);                  // CC f32

    k_gemm<<<dim3(NHH / 64, TT / 64, 2), dim3(256), 0, stream>>>(x, Wh, Wz, bz, XH, XZ);
    k_recur<<<dim3(256), dim3(256), 0, stream>>>(XH, XZ, Uh, Uz, zt0, ht0, hp0, Hbuf);
    k_logits<<<dim3(250), dim3(256), 0, stream>>>(Hbuf, Wout, lg);
    k_softmax<<<dim3(1), dim3(1024), 0, stream>>>(lg, out);
}